// Round 1
// baseline (422.015 us; speedup 1.0000x reference)
//
#include <hip/hip_runtime.h>
#include <hip/hip_bf16.h>

typedef _Float16 half8 __attribute__((ext_vector_type(8)));
typedef float f32x4 __attribute__((ext_vector_type(4)));

#define KC 32
#define DD 128
#define LL 4
#define NCOL 192      // 32 q-cols + 32 r-cols + 128 z-cols
#define EPS 164       // epilogue staging row stride in floats (32 u + 128 z + 4 pad)
#define NBLK 256

// ---------------------------------------------------------------------------
// Precompute: per-component Woodbury factorization + weight matrix in
// MFMA B-fragment order (fp16).
// Slot packing for phase-1 partials (16 floats):
//  0..9  = lower-tri of L in (l,m) order
//  10..13= c[l] = sum_d MU*iD*A[:,l]
//  14    = t_const = sum_d iD*MU^2
//  15    = sum_d log(D^2)
// ---------------------------------------------------------------------------
__global__ __launch_bounds__(256) void mfa_precompute(
    const float* __restrict__ MU, const float* __restrict__ A,
    const float* __restrict__ D, const float* __restrict__ PI,
    _Float16* __restrict__ wsw, float* __restrict__ wsc, float* __restrict__ wsh)
{
  __shared__ float sPart[KC][8][16];
  __shared__ float sRi[KC][LL][LL];
  const int tid = threadIdx.x;
  const int k = tid >> 3;        // 0..31
  const int sub = tid & 7;       // 0..7 -> each handles 16 d's

  // phase 1: partial accumulation
  {
    float p[16];
#pragma unroll
    for (int i = 0; i < 16; ++i) p[i] = 0.f;
    const int d0 = sub * 16;
    for (int di = 0; di < 16; ++di) {
      const int d = d0 + di;
      const float Dv = D[k*DD + d];
      const float id = 1.0f/(Dv*Dv);
      const float mu = MU[k*DD + d];
      float a[LL];
#pragma unroll
      for (int l = 0; l < LL; ++l) a[l] = A[(k*DD + d)*LL + l];
      int s = 0;
#pragma unroll
      for (int l = 0; l < LL; ++l) {
#pragma unroll
        for (int m2 = 0; m2 <= l; ++m2) { p[s] += a[l]*id*a[m2]; ++s; }
        p[10 + l] += mu*id*a[l];
      }
      p[14] += id*mu*mu;
      p[15] += logf(Dv*Dv);
    }
#pragma unroll
    for (int i = 0; i < 16; ++i) sPart[k][sub][i] = p[i];
  }
  __syncthreads();

  if (tid < KC) {
    const int kk = tid;
    float p[16];
#pragma unroll
    for (int i = 0; i < 16; ++i) p[i] = 0.f;
    for (int s = 0; s < 8; ++s)
#pragma unroll
      for (int i = 0; i < 16; ++i) p[i] += sPart[kk][s][i];

    // unpack L (lower)
    float Lm[LL][LL];
    {
      int s = 0;
      for (int l = 0; l < LL; ++l)
        for (int m2 = 0; m2 <= l; ++m2) { Lm[l][m2] = p[s]; ++s; }
    }
    for (int l = 0; l < LL; ++l) Lm[l][l] += 1.0f;
    float c[LL];
    for (int l = 0; l < LL; ++l) c[l] = p[10 + l];
    const float t_const  = p[14];
    const float sumlogD2 = p[15];

    // Cholesky: L = Lo * Lo^T  (lower)
    float Lo[LL][LL];
    for (int i = 0; i < LL; ++i)
      for (int j = 0; j < LL; ++j) Lo[i][j] = 0.f;
    for (int i = 0; i < LL; ++i) {
      float s = Lm[i][i];
      for (int m2 = 0; m2 < i; ++m2) s -= Lo[i][m2]*Lo[i][m2];
      Lo[i][i] = sqrtf(s);
      for (int j = i + 1; j < LL; ++j) {
        float t = Lm[j][i];
        for (int m2 = 0; m2 < i; ++m2) t -= Lo[j][m2]*Lo[i][m2];
        Lo[j][i] = t / Lo[i][i];
      }
    }
    // Ri = Lo^{-1} (lower). Then iL = Ri^T Ri, term2 = |Ri y|^2.
    float Ri[LL][LL];
    for (int i = 0; i < LL; ++i)
      for (int j = 0; j < LL; ++j) Ri[i][j] = 0.f;
    for (int i = 0; i < LL; ++i) {
      Ri[i][i] = 1.0f/Lo[i][i];
      for (int j = 0; j < i; ++j) {
        float s = 0.f;
        for (int m2 = j; m2 < i; ++m2) s += Lo[i][m2]*Ri[m2][j];
        Ri[i][j] = -s / Lo[i][i];
      }
    }
    for (int i = 0; i < LL; ++i)
      for (int j = 0; j < LL; ++j) sRi[kk][i][j] = Ri[i][j];
    // h = Ri c
    for (int l = 0; l < LL; ++l) {
      float s = 0.f;
      for (int m2 = 0; m2 <= l; ++m2) s += Ri[l][m2]*c[m2];
      wsh[kk*LL + l] = s;
    }
    float logdetL = 0.f;
    for (int i = 0; i < LL; ++i) logdetL += logf(Lo[i][i]);
    logdetL *= 2.0f;
    const float dlog2pi = 235.24826473f;  // 128*log(2*pi)
    wsc[kk] = PI[kk] - 0.5f*(dlog2pi + logdetL + sumlogD2) - 0.5f*t_const;
  }
  __syncthreads();

  // phase 2: weight matrix in fragment order.
  // idx = (t<<11) + (s<<9) + (lane<<3) + j8
  // element = W[col = t*16 + (lane&15)][dd = s*32 + (lane>>4)*8 + j8]
  for (int idx = tid; idx < NCOL*DD; idx += blockDim.x) {
    const int j8   = idx & 7;
    const int lane = (idx >> 3) & 63;
    const int s    = (idx >> 9) & 3;
    const int t    = idx >> 11;
    const int col  = t*16 + (lane & 15);
    const int dd   = s*32 + ((lane >> 4) << 3) + j8;
    float v;
    if (col < 32) {                       // q columns: iD (paired with x^2 frags)
      const float Dv = D[col*DD + dd];
      v = 1.0f/(Dv*Dv);
    } else if (col < 64) {                // r columns: iD*MU
      const int kk = col - 32;
      const float Dv = D[kk*DD + dd];
      v = MU[kk*DD + dd]/(Dv*Dv);
    } else {                              // z columns: G = iD * (A @ Ri^T)
      const int kk = (col - 64) >> 2, l = (col - 64) & 3;
      const float Dv = D[kk*DD + dd];
      const float id = 1.0f/(Dv*Dv);
      float s2 = 0.f;
      for (int m2 = 0; m2 <= l; ++m2) s2 += A[(kk*DD + dd)*LL + m2]*sRi[kk][l][m2];
      v = id*s2;
    }
    wsw[idx] = (_Float16)v;
  }
}

// ---------------------------------------------------------------------------
// Main kernel: 4 waves/block, each wave owns a 16-row tile per iteration.
// ---------------------------------------------------------------------------
__global__ __launch_bounds__(256) void mfa_main(
    const float* __restrict__ x, const _Float16* __restrict__ wsw,
    const float* __restrict__ wsc, const float* __restrict__ wsh,
    float* __restrict__ out, int N, int ntiles, int iters)
{
  __shared__ int4 sWbuf[3072];                    // 48 KB weights (fragment order)
  __shared__ alignas(16) float sC[KC];
  __shared__ alignas(16) float sH[KC*LL];
  __shared__ alignas(16) float sEp[4][16*EPS];    // 41984 B epilogue staging
  const int tid = threadIdx.x;

  {
    const int4* src = (const int4*)wsw;
    for (int i = tid; i < 3072; i += 256) sWbuf[i] = src[i];
    if (tid < KC) sC[tid] = wsc[tid];
    if (tid < KC*LL) sH[tid] = wsh[tid];
  }
  __syncthreads();

  const half8* sW8 = (const half8*)sWbuf;
  const int wv = tid >> 6, lane = tid & 63;
  const int m = lane & 15, g = lane >> 4;
  float* ep = &sEp[wv][0];

  for (int it = 0; it < iters; ++it) {
    const int tile = it*(NBLK*4) + (int)blockIdx.x*4 + wv;
    const bool valid = tile < ntiles;
    f32x4 acc[12];

    if (valid) {
      int row = tile*16 + m;
      if (row >= N) row = N - 1;
      const float* xr = x + (size_t)row*DD + g*8;
      half8 ax[4], ax2[4];
#pragma unroll
      for (int s = 0; s < 4; ++s) {
        const float4 v0 = *(const float4*)(xr + s*32);
        const float4 v1 = *(const float4*)(xr + s*32 + 4);
        half8 h, h2;
        h[0] = (_Float16)v0.x; h[1] = (_Float16)v0.y;
        h[2] = (_Float16)v0.z; h[3] = (_Float16)v0.w;
        h[4] = (_Float16)v1.x; h[5] = (_Float16)v1.y;
        h[6] = (_Float16)v1.z; h[7] = (_Float16)v1.w;
        h2[0] = (_Float16)(v0.x*v0.x); h2[1] = (_Float16)(v0.y*v0.y);
        h2[2] = (_Float16)(v0.z*v0.z); h2[3] = (_Float16)(v0.w*v0.w);
        h2[4] = (_Float16)(v1.x*v1.x); h2[5] = (_Float16)(v1.y*v1.y);
        h2[6] = (_Float16)(v1.z*v1.z); h2[7] = (_Float16)(v1.w*v1.w);
        ax[s] = h; ax2[s] = h2;
      }
#pragma unroll
      for (int t = 0; t < 12; ++t)
#pragma unroll
        for (int r = 0; r < 4; ++r) acc[t][r] = 0.f;

#pragma unroll
      for (int s = 0; s < 4; ++s) {
#pragma unroll
        for (int t = 0; t < 12; ++t) {
          const half8 b = sW8[(t*4 + s)*64 + lane];
          acc[t] = __builtin_amdgcn_mfma_f32_16x16x32_f16(
              (t < 2) ? ax2[s] : ax[s], b, acc[t], 0, 0, 0);
        }
      }
    }

    __syncthreads();   // protects sEp reuse (WAR vs previous iteration reads)

    if (valid) {
      // u = -0.5*q + r : tiles 0/2 and 1/3 share (row,col) residency.
      f32x4 u0, u1;
#pragma unroll
      for (int r = 0; r < 4; ++r) {
        u0[r] = acc[2][r] - 0.5f*acc[0][r];
        u1[r] = acc[3][r] - 0.5f*acc[1][r];
      }
      // C layout: row = g*4 + r, col = m  (m89-verified, dtype-independent)
#pragma unroll
      for (int r = 0; r < 4; ++r) {
        ep[(g*4 + r)*EPS + m]       = u0[r];
        ep[(g*4 + r)*EPS + 16 + m]  = u1[r];
      }
#pragma unroll
      for (int t = 4; t < 12; ++t)
#pragma unroll
        for (int r = 0; r < 4; ++r)
          ep[(g*4 + r)*EPS + 32 + (t - 4)*16 + m] = acc[t][r];
    }

    __syncthreads();   // publish staging to other lanes of the wave

    if (valid) {
      // epilogue: lane handles row m, k-group g (8 components)
      const float* eprow = ep + m*EPS;
      float ll[8];
      float lmax = -3.0e38f;
#pragma unroll
      for (int i = 0; i < 8; ++i) {
        const int k = g*8 + i;
        const float u = eprow[k];
        const float4 z = *(const float4*)(eprow + 32 + 4*k);
        const float4 h = *(const float4*)(sH + 4*k);
        const float z0 = z.x - h.x, z1 = z.y - h.y;
        const float z2 = z.z - h.z, z3 = z.w - h.w;
        const float t2 = z0*z0 + z1*z1 + z2*z2 + z3*z3;
        const float v = sC[k] + u + 0.5f*t2;
        ll[i] = v;
        lmax = fmaxf(lmax, v);
      }
      lmax = fmaxf(lmax, __shfl_xor(lmax, 16));
      lmax = fmaxf(lmax, __shfl_xor(lmax, 32));
      float sum = 0.f;
#pragma unroll
      for (int i = 0; i < 8; ++i) sum += __expf(ll[i] - lmax);
      sum += __shfl_xor(sum, 16);
      sum += __shfl_xor(sum, 32);
      if (g == 0) {
        const int n = tile*16 + m;
        if (n < N) out[n] = lmax + __logf(sum);
      }
    }
  }
}

extern "C" void kernel_launch(void* const* d_in, const int* in_sizes, int n_in,
                              void* d_out, int out_size, void* d_ws, size_t ws_size,
                              hipStream_t stream) {
  const float* x  = (const float*)d_in[0];
  const float* MU = (const float*)d_in[1];
  const float* A  = (const float*)d_in[2];
  const float* D  = (const float*)d_in[3];
  const float* PI = (const float*)d_in[4];
  float* out = (float*)d_out;

  const int N = in_sizes[0] / DD;
  _Float16* wsw = (_Float16*)d_ws;
  float* wsc = (float*)((char*)d_ws + (size_t)NCOL*DD*sizeof(_Float16)); // +49152
  float* wsh = wsc + KC;

  hipLaunchKernelGGL(mfa_precompute, dim3(1), dim3(256), 0, stream,
                     MU, A, D, PI, wsw, wsc, wsh);

  const int ntiles = (N + 15) / 16;
  const int iters  = (ntiles + NBLK*4 - 1) / (NBLK*4);
  hipLaunchKernelGGL(mfa_main, dim3(NBLK), dim3(256), 0, stream,
                     x, wsw, wsc, wsh, out, N, ntiles, iters);
}

// Round 2
// 401.575 us; speedup vs baseline: 1.0509x; 1.0509x over previous
//
#include <hip/hip_runtime.h>
#include <hip/hip_bf16.h>

typedef _Float16 half8 __attribute__((ext_vector_type(8)));
typedef float f32x4 __attribute__((ext_vector_type(4)));

#define KC 32
#define DD 128
#define LL 4
#define NCOL 192      // 32 q-cols + 32 r-cols + 128 z-cols
#define NBLK 768      // 3 blocks/CU (LDS-capped at 48KB/block)

// ---------------------------------------------------------------------------
// Precompute: per-component Woodbury factorization + weight matrix in
// MFMA B-fragment order (fp16).
// Slot packing for phase-1 partials (16 floats):
//  0..9  = lower-tri of L in (l,m) order
//  10..13= c[l] = sum_d MU*iD*A[:,l]
//  14    = t_const = sum_d iD*MU^2
//  15    = sum_d log(D^2)
// ---------------------------------------------------------------------------
__global__ __launch_bounds__(256) void mfa_precompute(
    const float* __restrict__ MU, const float* __restrict__ A,
    const float* __restrict__ D, const float* __restrict__ PI,
    _Float16* __restrict__ wsw, float* __restrict__ wsc, float* __restrict__ wsh)
{
  __shared__ float sPart[KC][8][16];
  __shared__ float sRi[KC][LL][LL];
  const int tid = threadIdx.x;
  const int k = tid >> 3;        // 0..31
  const int sub = tid & 7;       // 0..7 -> each handles 16 d's

  // phase 1: partial accumulation
  {
    float p[16];
#pragma unroll
    for (int i = 0; i < 16; ++i) p[i] = 0.f;
    const int d0 = sub * 16;
    for (int di = 0; di < 16; ++di) {
      const int d = d0 + di;
      const float Dv = D[k*DD + d];
      const float id = 1.0f/(Dv*Dv);
      const float mu = MU[k*DD + d];
      float a[LL];
#pragma unroll
      for (int l = 0; l < LL; ++l) a[l] = A[(k*DD + d)*LL + l];
      int s = 0;
#pragma unroll
      for (int l = 0; l < LL; ++l) {
#pragma unroll
        for (int m2 = 0; m2 <= l; ++m2) { p[s] += a[l]*id*a[m2]; ++s; }
        p[10 + l] += mu*id*a[l];
      }
      p[14] += id*mu*mu;
      p[15] += logf(Dv*Dv);
    }
#pragma unroll
    for (int i = 0; i < 16; ++i) sPart[k][sub][i] = p[i];
  }
  __syncthreads();

  if (tid < KC) {
    const int kk = tid;
    float p[16];
#pragma unroll
    for (int i = 0; i < 16; ++i) p[i] = 0.f;
    for (int s = 0; s < 8; ++s)
#pragma unroll
      for (int i = 0; i < 16; ++i) p[i] += sPart[kk][s][i];

    // unpack L (lower)
    float Lm[LL][LL];
    {
      int s = 0;
      for (int l = 0; l < LL; ++l)
        for (int m2 = 0; m2 <= l; ++m2) { Lm[l][m2] = p[s]; ++s; }
    }
    for (int l = 0; l < LL; ++l) Lm[l][l] += 1.0f;
    float c[LL];
    for (int l = 0; l < LL; ++l) c[l] = p[10 + l];
    const float t_const  = p[14];
    const float sumlogD2 = p[15];

    // Cholesky: L = Lo * Lo^T  (lower)
    float Lo[LL][LL];
    for (int i = 0; i < LL; ++i)
      for (int j = 0; j < LL; ++j) Lo[i][j] = 0.f;
    for (int i = 0; i < LL; ++i) {
      float s = Lm[i][i];
      for (int m2 = 0; m2 < i; ++m2) s -= Lo[i][m2]*Lo[i][m2];
      Lo[i][i] = sqrtf(s);
      for (int j = i + 1; j < LL; ++j) {
        float t = Lm[j][i];
        for (int m2 = 0; m2 < i; ++m2) t -= Lo[j][m2]*Lo[i][m2];
        Lo[j][i] = t / Lo[i][i];
      }
    }
    // Ri = Lo^{-1} (lower). term2 = |Ri y|^2.
    float Ri[LL][LL];
    for (int i = 0; i < LL; ++i)
      for (int j = 0; j < LL; ++j) Ri[i][j] = 0.f;
    for (int i = 0; i < LL; ++i) {
      Ri[i][i] = 1.0f/Lo[i][i];
      for (int j = 0; j < i; ++j) {
        float s = 0.f;
        for (int m2 = j; m2 < i; ++m2) s += Lo[i][m2]*Ri[m2][j];
        Ri[i][j] = -s / Lo[i][i];
      }
    }
    for (int i = 0; i < LL; ++i)
      for (int j = 0; j < LL; ++j) sRi[kk][i][j] = Ri[i][j];
    // h = Ri c
    for (int l = 0; l < LL; ++l) {
      float s = 0.f;
      for (int m2 = 0; m2 <= l; ++m2) s += Ri[l][m2]*c[m2];
      wsh[kk*LL + l] = s;
    }
    float logdetL = 0.f;
    for (int i = 0; i < LL; ++i) logdetL += logf(Lo[i][i]);
    logdetL *= 2.0f;
    const float dlog2pi = 235.24826473f;  // 128*log(2*pi)
    wsc[kk] = PI[kk] - 0.5f*(dlog2pi + logdetL + sumlogD2) - 0.5f*t_const;
  }
  __syncthreads();

  // phase 2: weight matrix in B-fragment order.
  // idx = (t<<11) + (s<<9) + (lane<<3) + j8
  // element = W[col = t*16 + (lane&15)][dd = s*32 + (lane>>4)*8 + j8]
  for (int idx = tid; idx < NCOL*DD; idx += blockDim.x) {
    const int j8   = idx & 7;
    const int lane = (idx >> 3) & 63;
    const int s    = (idx >> 9) & 3;
    const int t    = idx >> 11;
    const int col  = t*16 + (lane & 15);
    const int dd   = s*32 + ((lane >> 4) << 3) + j8;
    float v;
    if (col < 32) {                       // q columns: iD (paired with x^2 frags)
      const float Dv = D[col*DD + dd];
      v = 1.0f/(Dv*Dv);
    } else if (col < 64) {                // r columns: iD*MU
      const int kk = col - 32;
      const float Dv = D[kk*DD + dd];
      v = MU[kk*DD + dd]/(Dv*Dv);
    } else {                              // z columns: G = iD * (A @ Ri^T)
      const int kk = (col - 64) >> 2, l = (col - 64) & 3;
      const float Dv = D[kk*DD + dd];
      const float id = 1.0f/(Dv*Dv);
      float s2 = 0.f;
      for (int m2 = 0; m2 <= l; ++m2) s2 += A[(kk*DD + dd)*LL + m2]*sRi[kk][l][m2];
      v = id*s2;
    }
    wsw[idx] = (_Float16)v;
  }
}

// ---------------------------------------------------------------------------
// Main kernel: 4 waves/block, each wave owns a 16-row tile per iteration.
// Epilogue is all-shuffle (no LDS staging, no in-loop barriers) so LDS
// stays at 48KB -> 3 blocks/CU, 12 waves/CU.
// ---------------------------------------------------------------------------
__global__ __launch_bounds__(256, 3) void mfa_main(
    const float* __restrict__ x, const _Float16* __restrict__ wsw,
    const float* __restrict__ wsc, const float* __restrict__ wsh,
    float* __restrict__ out, int N, int ntiles, int iters)
{
  __shared__ int4 sWbuf[3072];                    // 48 KB weights (fragment order)
  const int tid = threadIdx.x;

  {
    const int4* src = (const int4*)wsw;
    for (int i = tid; i < 3072; i += 256) sWbuf[i] = src[i];
  }

  const half8* sW8 = (const half8*)sWbuf;
  const int wv = tid >> 6, lane = tid & 63;
  const int m = lane & 15, g = lane >> 4;
  const int q = m >> 2;
  const int gbase = lane & 48;                    // g*16

  // per-lane constants: c0/c1 pair with k=m and k=m+16; hh[j] = h[(j*16+m)]
  const float c0 = wsc[m];
  const float c1 = wsc[16 + m];
  float hh[8];
#pragma unroll
  for (int j = 0; j < 8; ++j) hh[j] = wsh[j*16 + m];

  __syncthreads();   // weights visible to all waves

  for (int it = 0; it < iters; ++it) {
    const int tile = it*(NBLK*4) + (int)blockIdx.x*4 + wv;
    if (tile >= ntiles) continue;

    // ---- load 16 rows of x, build A-fragments (value + squared) ----
    const int row = tile*16 + m;                  // N % 16 == 0, always in-bounds
    const float* xr = x + (size_t)row*DD + g*8;
    half8 ax[4], ax2[4];
#pragma unroll
    for (int s = 0; s < 4; ++s) {
      const float4 v0 = *(const float4*)(xr + s*32);
      const float4 v1 = *(const float4*)(xr + s*32 + 4);
      half8 h, h2;
      h[0] = (_Float16)v0.x; h[1] = (_Float16)v0.y;
      h[2] = (_Float16)v0.z; h[3] = (_Float16)v0.w;
      h[4] = (_Float16)v1.x; h[5] = (_Float16)v1.y;
      h[6] = (_Float16)v1.z; h[7] = (_Float16)v1.w;
      h2[0] = (_Float16)(v0.x*v0.x); h2[1] = (_Float16)(v0.y*v0.y);
      h2[2] = (_Float16)(v0.z*v0.z); h2[3] = (_Float16)(v0.w*v0.w);
      h2[4] = (_Float16)(v1.x*v1.x); h2[5] = (_Float16)(v1.y*v1.y);
      h2[6] = (_Float16)(v1.z*v1.z); h2[7] = (_Float16)(v1.w*v1.w);
      ax[s] = h; ax2[s] = h2;
    }

    f32x4 acc[12];
#pragma unroll
    for (int t = 0; t < 12; ++t)
#pragma unroll
      for (int r = 0; r < 4; ++r) acc[t][r] = 0.f;

#pragma unroll
    for (int s = 0; s < 4; ++s) {
#pragma unroll
      for (int t = 0; t < 12; ++t) {
        const half8 b = sW8[(t*4 + s)*64 + lane];
        acc[t] = __builtin_amdgcn_mfma_f32_16x16x32_f16(
            (t < 2) ? ax2[s] : ax[s], b, acc[t], 0, 0, 0);
      }
    }

    // ---- shuffle epilogue ----
    // C layout: row = g*4 + r, col = m-of-tile t (col = t*16+m).
    // u terms (k=m and k=m+16), fold in per-k constant:
    float vp0[4], vp1[4];
#pragma unroll
    for (int r = 0; r < 4; ++r) {
      vp0[r] = acc[2][r] - 0.5f*acc[0][r] + c0;
      vp1[r] = acc[3][r] - 0.5f*acc[1][r] + c1;
    }
    // term2: lane holds z[k = j*4 + q][l = m&3] for j=0..7; quad-reduce over l.
    float t2[8][4];
#pragma unroll
    for (int j = 0; j < 8; ++j)
#pragma unroll
      for (int r = 0; r < 4; ++r) {
        float e = acc[j + 4][r] - hh[j];
        e = e*e;
        e += __shfl_xor(e, 1);
        e += __shfl_xor(e, 2);
        t2[j][r] = e;
      }
    // gather u for this lane's 8 k's (k = 4*j + q), combine, logsumexp over 32 k.
    float res[4];
#pragma unroll
    for (int r = 0; r < 4; ++r) {
      float v[8];
#pragma unroll
      for (int jj = 0; jj < 4; ++jj) {
        const int src = gbase + 4*jj + q;
        v[jj]     = __shfl(vp0[r], src) + 0.5f*t2[jj][r];
        v[jj + 4] = __shfl(vp1[r], src) + 0.5f*t2[jj + 4][r];
      }
      float mx = v[0];
#pragma unroll
      for (int i = 1; i < 8; ++i) mx = fmaxf(mx, v[i]);
      mx = fmaxf(mx, __shfl_xor(mx, 4));
      mx = fmaxf(mx, __shfl_xor(mx, 8));
      float sum = 0.f;
#pragma unroll
      for (int i = 0; i < 8; ++i) sum += __expf(v[i] - mx);
      sum += __shfl_xor(sum, 4);
      sum += __shfl_xor(sum, 8);
      res[r] = mx + __logf(sum);
    }
    if (m == 0) {
      float4 o; o.x = res[0]; o.y = res[1]; o.z = res[2]; o.w = res[3];
      *(float4*)(out + (size_t)tile*16 + g*4) = o;
    }
  }
}

extern "C" void kernel_launch(void* const* d_in, const int* in_sizes, int n_in,
                              void* d_out, int out_size, void* d_ws, size_t ws_size,
                              hipStream_t stream) {
  const float* x  = (const float*)d_in[0];
  const float* MU = (const float*)d_in[1];
  const float* A  = (const float*)d_in[2];
  const float* D  = (const float*)d_in[3];
  const float* PI = (const float*)d_in[4];
  float* out = (float*)d_out;

  const int N = in_sizes[0] / DD;
  _Float16* wsw = (_Float16*)d_ws;
  float* wsc = (float*)((char*)d_ws + (size_t)NCOL*DD*sizeof(_Float16)); // +49152
  float* wsh = wsc + KC;

  hipLaunchKernelGGL(mfa_precompute, dim3(1), dim3(256), 0, stream,
                     MU, A, D, PI, wsw, wsc, wsh);

  const int ntiles = (N + 15) / 16;
  const int iters  = (ntiles + NBLK*4 - 1) / (NBLK*4);
  hipLaunchKernelGGL(mfa_main, dim3(NBLK), dim3(256), 0, stream,
                     x, wsw, wsc, wsh, out, N, ntiles, iters);
}